// Round 9
// baseline (240.411 us; speedup 1.0000x reference)
//
#include <hip/hip_runtime.h>

#define DD 128
#define BINCAP 4608     // coarse bin capacity: mean 4092 + 8 sigma
#define S1_EPB 7168     // edges per stage-1 block (7 per thread x 1024)
#define DEG_R 16384     // deg privatization range (64KB LDS)
#define DEG_S 16        // deg slices

typedef __attribute__((ext_vector_type(8))) short short8;
typedef __attribute__((ext_vector_type(4))) float f32x4;

__device__ __forceinline__ unsigned short f2bf(float f) {
    unsigned int u; __builtin_memcpy(&u, &f, 4);
    unsigned int r = (u + 0x7FFFu + ((u >> 16) & 1u)) >> 16;
    return (unsigned short)r;
}
__device__ __forceinline__ unsigned int pack_bf(float a, float b) {
    return (unsigned int)f2bf(a) | ((unsigned int)f2bf(b) << 16);
}
__device__ __forceinline__ float lo_bf(unsigned int p) {
    unsigned int u = (p & 0xFFFFu) << 16; float f; __builtin_memcpy(&f, &u, 4); return f;
}
__device__ __forceinline__ float hi_bf(unsigned int p) {
    unsigned int u = p & 0xFFFF0000u; float f; __builtin_memcpy(&f, &u, 4); return f;
}
__device__ __forceinline__ float i2f(int v) { float f; __builtin_memcpy(&f, &v, 4); return f; }
__device__ __forceinline__ int f2i(float v) { int i; __builtin_memcpy(&i, &v, 4); return i; }

// ---------- prep: W swizzle into MFMA B-fragment order (bf16) ----------
__global__ void k_wprep(const float* __restrict__ W, unsigned short* __restrict__ Wfrag) {
    int i = blockIdx.x * 256 + threadIdx.x;   // 0..16383
    int k = i >> 7, n = i & 127;
    int tt = n >> 4, s = k >> 5, l = (((k >> 3) & 3) << 4) | (n & 15), j = k & 7;
    Wfrag[((tt * 4 + s) * 64 + l) * 8 + j] = f2bf(W[k * DD + n]);
}

// ---------- fused: stage1 coarse binning + deg privatized histogram + MFMA GEMM ----------
// deg holds edge-only out-degree (self loop's +1 applied at use site).
__global__ __launch_bounds__(1024) void k_fused(
    const int* __restrict__ ei, const float* __restrict__ ew,
    int* __restrict__ deg, int* __restrict__ cursor, long long* __restrict__ coarse,
    int E, int N, int NBIN, int nS1i, int nDeg,
    const float* __restrict__ x, const unsigned short* __restrict__ Wfrag,
    const float* __restrict__ b, unsigned short* __restrict__ h)
{
    __shared__ int smem[16384];   // 64KB, carved per role
    int t = threadIdx.x;
    int id = blockIdx.x;
    int role, rid;
    if (id < 2 * nS1i)           { role = (id & 1); rid = id >> 1; }          // 0=stage1, 1=gemm
    else if (id < 2 * nS1i + nDeg) { role = 2; rid = id - 2 * nS1i; }         // deg
    else                         { role = 1; rid = nS1i + (id - 2 * nS1i - nDeg); }

    const int* row = ei;
    const int* col = ei + E;

    if (role == 0) {
        // ===== stage 1: bin 7168 edges by dest>>8, copy out in bin-runs =====
        int* scnt  = smem;            // 512
        int* soff  = smem + 512;      // 512
        int* gbase = smem + 1024;     // NBIN (<512)
        long long* sorted = (long long*)(smem + 1536);   // S1_EPB entries
        for (int i = t; i < 512; i += 1024) scnt[i] = 0;
        __syncthreads();
        int e0 = rid * S1_EPB;
        int myrank[7];
#pragma unroll
        for (int j = 0; j < 7; ++j) {
            int e = e0 + j * 1024 + t;
            if (e < E) myrank[j] = atomicAdd(&scnt[col[e] >> 8], 1);
        }
        __syncthreads();
        if (t < 512) soff[t] = scnt[t];
        __syncthreads();
        for (int off = 1; off < 512; off <<= 1) {
            int v = 0;
            if (t < 512 && t >= off) v = soff[t - off];
            __syncthreads();
            if (t < 512) soff[t] += v;
            __syncthreads();
        }
        if (t < NBIN && scnt[t] > 0) gbase[t] = atomicAdd(&cursor[t], scnt[t]);
#pragma unroll
        for (int j = 0; j < 7; ++j) {
            int e = e0 + j * 1024 + t;
            if (e < E) {
                int c = col[e];
                int bn = c >> 8;
                int lo = row[e] | ((c & 255) << 17);
                long long ent = ((long long)(unsigned)f2i(ew[e]) << 32) | (unsigned)lo;
                sorted[(soff[bn] - scnt[bn]) + myrank[j]] = ent;
            }
        }
        __syncthreads();
        int wave = t >> 6, lane = t & 63;
        for (int bn = wave; bn < NBIN; bn += 16) {
            int k = scnt[bn];
            if (k == 0) continue;
            int off0 = soff[bn] - k;
            int gb = gbase[bn];
            long long* dst = coarse + (size_t)bn * BINCAP;
            for (int j = lane; j < k; j += 64) {
                int gp = gb + j;
                if (gp < BINCAP) dst[gp] = sorted[off0 + j];
            }
        }
        return;
    }
    if (role == 2) {
        // ===== deg: privatized (range, slice) histogram over sources =====
        int nr = (N + DEG_R - 1) / DEG_R;
        int ri = rid % nr, si = rid / nr;
        int* lc = smem;               // 16384
        for (int i = t; i < DEG_R; i += 1024) lc[i] = 0;
        __syncthreads();
        int base = ri * DEG_R;
        int per = (E + DEG_S - 1) / DEG_S;
        int es = si * per, ee = es + per; if (ee > E) ee = E;
        int q0 = es >> 2, q1 = ee >> 2;
        const int4* r4 = (const int4*)row;
        for (int q = q0 + t; q < q1; q += 1024) {
            int4 v = r4[q];
            unsigned d0 = (unsigned)(v.x - base), d1 = (unsigned)(v.y - base);
            unsigned d2 = (unsigned)(v.z - base), d3 = (unsigned)(v.w - base);
            if (d0 < DEG_R) atomicAdd(&lc[d0], 1);
            if (d1 < DEG_R) atomicAdd(&lc[d1], 1);
            if (d2 < DEG_R) atomicAdd(&lc[d2], 1);
            if (d3 < DEG_R) atomicAdd(&lc[d3], 1);
        }
        for (int e = (q1 << 2) + t; e < ee; e += 1024) {
            unsigned d = (unsigned)(row[e] - base);
            if (d < DEG_R) atomicAdd(&lc[d], 1);
        }
        __syncthreads();
        for (int i = t; i < DEG_R; i += 1024) {
            int node = base + i, k = lc[i];
            if (node < N && k) atomicAdd(&deg[node], k);
        }
        return;
    }
    // ===== GEMM: 256 rows/block (16 waves x 16 rows), h = bf16(x@W + b) =====
    int lane = t & 63, wave = t >> 6;
    int lrow0 = wave * 16;                 // local row base of this wave's strip
    int row0 = rid * 256 + lrow0;
    int mrow = row0 + (lane & 15);
    int kgrp = lane >> 4;
    f32x4 acc[8];
#pragma unroll
    for (int i = 0; i < 8; ++i) acc[i] = (f32x4){0.f, 0.f, 0.f, 0.f};
    const short8* Wf = (const short8*)Wfrag;
#pragma unroll
    for (int s = 0; s < 4; ++s) {
        float xv[8];
        if (mrow < N) {
            const float4* xp = (const float4*)(x + (size_t)mrow * DD + s * 32 + kgrp * 8);
            float4 xa = xp[0], xb = xp[1];
            xv[0] = xa.x; xv[1] = xa.y; xv[2] = xa.z; xv[3] = xa.w;
            xv[4] = xb.x; xv[5] = xb.y; xv[6] = xb.z; xv[7] = xb.w;
        } else {
#pragma unroll
            for (int j = 0; j < 8; ++j) xv[j] = 0.f;
        }
        short8 af;
#pragma unroll
        for (int j = 0; j < 8; ++j) af[j] = (short)f2bf(xv[j]);
#pragma unroll
        for (int tt = 0; tt < 8; ++tt) {
            short8 bf = Wf[(tt * 4 + s) * 64 + lane];
            acc[tt] = __builtin_amdgcn_mfma_f32_16x16x32_bf16(af, bf, acc[tt], 0, 0, 0);
        }
    }
    // epilogue: stage bf16 tile in LDS (64KB), then coalesced dwordx4 copy-out
    unsigned short* ht = (unsigned short*)smem;   // [256][128] bf16
    int drowl = lrow0 + (lane >> 4) * 4;          // local row of acc[.][0]
    int coll = lane & 15;
#pragma unroll
    for (int tt = 0; tt < 8; ++tt) {
        float bias = b[tt * 16 + coll];
#pragma unroll
        for (int rr = 0; rr < 4; ++rr)
            ht[(drowl + rr) * 128 + tt * 16 + coll] = f2bf(acc[tt][rr] + bias);
    }
    __syncthreads();
    int lim = N - rid * 256;                      // rows valid in this tile
    const int4* hts = (const int4*)smem;
    int4* hg = (int4*)(h + (size_t)rid * 256 * DD);
    for (int i = t; i < 4096; i += 1024) {        // 256 rows x 16 int4
        int lr = i >> 4;
        if (lr < lim) hg[i] = hts[i];
    }
}

// ---------- merged stage2 + aggregate + BN stats ----------
__global__ __launch_bounds__(1024) void k_agg(
    const long long* __restrict__ coarse, const int* __restrict__ cursor,
    const int* __restrict__ deg, const unsigned int* __restrict__ h,
    unsigned int* __restrict__ outb, float* __restrict__ colsumR,
    float* __restrict__ colsumsqR, int N)
{
    __shared__ long long sorted2[BINCAP];   // 36864B
    __shared__ int fcnt[256], fpos[256], fcur[256];
    __shared__ float ls[2048], lq[2048];    // 16KB
    int bn = blockIdx.x, t = threadIdx.x;
    int m = cursor[bn]; if (m > BINCAP) m = BINCAP;
    for (int i = t; i < 256; i += 1024) fcnt[i] = 0;
    __syncthreads();
    const long long* src = coarse + (size_t)bn * BINCAP;
    for (int i = t; i < m; i += 1024) {
        int lo = (int)src[i];
        atomicAdd(&fcnt[(lo >> 17) & 255], 1);
    }
    __syncthreads();
    if (t < 256) fpos[t] = fcnt[t];
    __syncthreads();
    for (int off = 1; off < 256; off <<= 1) {
        int v = 0;
        if (t < 256 && t >= off) v = fpos[t - off];
        __syncthreads();
        if (t < 256) fpos[t] += v;
        __syncthreads();
    }
    if (t < 256) fcur[t] = fpos[t] - fcnt[t];
    __syncthreads();
    for (int i = t; i < m; i += 1024) {
        long long v = src[i];
        int lo = (int)v;
        int clo = (lo >> 17) & 255;
        int sr = lo & 0x1FFFF;
        int c = (bn << 8) + clo;
        // full norm (self loop +1 on both degrees), computed ONCE per edge:
        float w = rsqrtf((float)(deg[sr] + 1)) * rsqrtf((float)(deg[c] + 1)) * i2f((int)(v >> 32));
        int p = atomicAdd(&fcur[clo], 1);
        sorted2[p] = ((long long)(unsigned)f2i(w) << 32) | (unsigned)sr;
    }
    __syncthreads();
    int wave = t >> 6, lane = t & 63;
    float s0 = 0, s1 = 0, q0 = 0, q1 = 0;
    const int2* sp = (const int2*)sorted2;
    for (int d = wave; d < 256; d += 16) {
        int c = (bn << 8) + d;
        if (c >= N) continue;
        float dn = rsqrtf((float)(deg[c] + 1));
        float sn = dn * dn;   // self-loop weight
        unsigned int p = h[(size_t)c * 64 + lane];
        float a0 = sn * lo_bf(p), a1 = sn * hi_bf(p);
        int cn = fcnt[d];
        int off0 = fpos[d] - cn;
        int j = 0;
        for (; j + 8 <= cn; j += 8) {
            int2 d0 = sp[off0 + j],     d1 = sp[off0 + j + 1];
            int2 d2 = sp[off0 + j + 2], d3 = sp[off0 + j + 3];
            int2 d4 = sp[off0 + j + 4], d5 = sp[off0 + j + 5];
            int2 d6 = sp[off0 + j + 6], d7 = sp[off0 + j + 7];
            unsigned int g0 = h[(size_t)d0.x * 64 + lane];
            unsigned int g1 = h[(size_t)d1.x * 64 + lane];
            unsigned int g2 = h[(size_t)d2.x * 64 + lane];
            unsigned int g3 = h[(size_t)d3.x * 64 + lane];
            unsigned int g4 = h[(size_t)d4.x * 64 + lane];
            unsigned int g5 = h[(size_t)d5.x * 64 + lane];
            unsigned int g6 = h[(size_t)d6.x * 64 + lane];
            unsigned int g7 = h[(size_t)d7.x * 64 + lane];
            float w0 = i2f(d0.y), w1 = i2f(d1.y), w2 = i2f(d2.y), w3 = i2f(d3.y);
            float w4 = i2f(d4.y), w5 = i2f(d5.y), w6 = i2f(d6.y), w7 = i2f(d7.y);
            a0 = fmaf(w0, lo_bf(g0), a0); a1 = fmaf(w0, hi_bf(g0), a1);
            a0 = fmaf(w1, lo_bf(g1), a0); a1 = fmaf(w1, hi_bf(g1), a1);
            a0 = fmaf(w2, lo_bf(g2), a0); a1 = fmaf(w2, hi_bf(g2), a1);
            a0 = fmaf(w3, lo_bf(g3), a0); a1 = fmaf(w3, hi_bf(g3), a1);
            a0 = fmaf(w4, lo_bf(g4), a0); a1 = fmaf(w4, hi_bf(g4), a1);
            a0 = fmaf(w5, lo_bf(g5), a0); a1 = fmaf(w5, hi_bf(g5), a1);
            a0 = fmaf(w6, lo_bf(g6), a0); a1 = fmaf(w6, hi_bf(g6), a1);
            a0 = fmaf(w7, lo_bf(g7), a0); a1 = fmaf(w7, hi_bf(g7), a1);
        }
        for (; j < cn; ++j) {
            int2 dd = sp[off0 + j];
            unsigned int g = h[(size_t)dd.x * 64 + lane];
            float w = i2f(dd.y);
            a0 = fmaf(w, lo_bf(g), a0);
            a1 = fmaf(w, hi_bf(g), a1);
        }
        outb[(size_t)c * 64 + lane] = pack_bf(a0, a1);
        s0 += a0; q0 += a0 * a0;
        s1 += a1; q1 += a1 * a1;
    }
    ls[wave * 128 + lane * 2] = s0; ls[wave * 128 + lane * 2 + 1] = s1;
    lq[wave * 128 + lane * 2] = q0; lq[wave * 128 + lane * 2 + 1] = q1;
    __syncthreads();
    if (t < 128) {
        float S = 0, Q = 0;
#pragma unroll
        for (int w = 0; w < 16; ++w) { S += ls[w * 128 + t]; Q += lq[w * 128 + t]; }
        int rep = (bn & 7) * 128 + t;
        atomicAdd(&colsumR[rep], S);
        atomicAdd(&colsumsqR[rep], Q);
    }
}

// ---------- merged BN finalize + apply + ReLU (uint2 in, float4 out) ----------
__global__ __launch_bounds__(256) void k_bn(
    const unsigned int* __restrict__ outb, float* __restrict__ out,
    const float* __restrict__ colsumR, const float* __restrict__ colsumsqR,
    const float* __restrict__ gamma, const float* __restrict__ beta,
    int N, int total32)
{
    __shared__ float ss[256];
    int t = threadIdx.x;
    if (t < 128) {
        float S = 0, Q = 0;
#pragma unroll
        for (int r = 0; r < 8; ++r) { S += colsumR[r * 128 + t]; Q += colsumsqR[r * 128 + t]; }
        float invN = 1.0f / (float)N;
        float mean = S * invN;
        float var = Q * invN - mean * mean;
        float inv = rsqrtf(var + 1e-5f);
        float sc = gamma[t] * inv;
        ss[t] = sc;
        ss[128 + t] = beta[t] - mean * sc;
    }
    __syncthreads();
    const uint2* ob = (const uint2*)outb;
    float4* o4 = (float4*)out;
    for (int i = blockIdx.x * 256 + t; i < total32; i += gridDim.x * 256) {
        int c0 = (i & 31) * 4;
        uint2 p = ob[i];
        float4 v;
        v.x = fmaxf(lo_bf(p.x) * ss[c0]     + ss[128 + c0],     0.0f);
        v.y = fmaxf(hi_bf(p.x) * ss[c0 + 1] + ss[128 + c0 + 1], 0.0f);
        v.z = fmaxf(lo_bf(p.y) * ss[c0 + 2] + ss[128 + c0 + 2], 0.0f);
        v.w = fmaxf(hi_bf(p.y) * ss[c0 + 3] + ss[128 + c0 + 3], 0.0f);
        o4[i] = v;
    }
}

extern "C" void kernel_launch(void* const* d_in, const int* in_sizes, int n_in,
                              void* d_out, int out_size, void* d_ws, size_t ws_size,
                              hipStream_t stream) {
    const float* x     = (const float*)d_in[0];
    const int* ei      = (const int*)d_in[1];
    const float* ew    = (const float*)d_in[2];
    const float* W     = (const float*)d_in[3];
    const float* b     = (const float*)d_in[4];
    const float* gamma = (const float*)d_in[5];
    const float* beta  = (const float*)d_in[6];
    float* out = (float*)d_out;

    int N = in_sizes[0] / DD;     // 100000
    int E = in_sizes[2];          // 1600000
    int NBIN = (N + 255) / 256;   // 391

    char* wsb = (char*)d_ws;
    size_t off = 0;
    auto alloc = [&](size_t bytes) -> char* {
        char* p = wsb + off;
        off = (off + bytes + 255) & ~(size_t)255;
        return p;
    };
    // one contiguous zero-init zone: deg | cursor | colsumR | colsumsqR
    size_t zwords = (size_t)N + NBIN + 1024 + 1024;
    int* zzone     = (int*)alloc(zwords * 4);
    int* deg       = zzone;
    int* cursor    = zzone + N;
    float* colsumR   = (float*)(zzone + N + NBIN);
    float* colsumsqR = colsumR + 1024;
    long long* coarse = (long long*)alloc((size_t)NBIN * BINCAP * 8);   // 14.4MB
    unsigned short* h = (unsigned short*)alloc((size_t)N * DD * 2);     // 25.6MB
    unsigned short* Wfrag = (unsigned short*)alloc(DD * DD * 2);
    unsigned int* outb = (unsigned int*)alloc((size_t)N * 64 * 4);      // 25.6MB bf16x2

    int nS1   = (E + S1_EPB - 1) / S1_EPB;          // 224
    int nGemm = (N + 255) / 256;                    // 391
    int nS1i  = (nS1 < nGemm) ? nS1 : nGemm;
    int nDeg  = ((N + DEG_R - 1) / DEG_R) * DEG_S;  // 7 * 16 = 112
    int GF    = 2 * nS1i + nDeg + (nGemm - nS1i);

    hipMemsetAsync(zzone, 0, zwords * 4, stream);
    k_wprep<<<dim3(64), dim3(256), 0, stream>>>(W, Wfrag);
    k_fused<<<dim3(GF), dim3(1024), 0, stream>>>(ei, ew, deg, cursor, coarse, E, N, NBIN,
                                                 nS1i, nDeg, x, Wfrag, b, h);
    k_agg<<<dim3(NBIN), dim3(1024), 0, stream>>>(coarse, cursor, deg, (const unsigned int*)h,
                                                 outb, colsumR, colsumsqR, N);
    k_bn<<<dim3(1024), dim3(256), 0, stream>>>(outb, out, colsumR, colsumsqR,
                                               gamma, beta, N, N * 32);
}